// Round 9
// baseline (606.588 us; speedup 1.0000x reference)
//
#include <hip/hip_runtime.h>
#include <math.h>

#define T_STEPS 2048
#define B_SZ 16
#define D_SZ 1024
#define N_SZ 64
#define M_ROWS (T_STEPS * B_SZ)   // 32768
#define NOUT (4 * N_SZ)           // 256
#define U_BLK 8
#define NBLK (T_STEPS / U_BLK)    // 256

typedef __attribute__((ext_vector_type(8))) short bf16x8;
typedef __attribute__((ext_vector_type(4))) float f32x4;

// ---------------------------------------------------------------------------
// DPP reductions.
// ---------------------------------------------------------------------------
template <int CTRL, int RMASK, bool BC>
__device__ __forceinline__ float dpp_add(float v) {
  return v + __int_as_float(__builtin_amdgcn_update_dpp(
                 0, __float_as_int(v), CTRL, RMASK, 0xF, BC));
}
// full reduce, uniform result (readlane) - used by norm/gram kernels
__device__ __forceinline__ float wave_red(float v) {
  v = dpp_add<0xB1, 0xF, true>(v);
  v = dpp_add<0x4E, 0xF, true>(v);
  v = dpp_add<0x141, 0xF, true>(v);
  v = dpp_add<0x140, 0xF, true>(v);
  v = dpp_add<0x142, 0xA, false>(v);
  v = dpp_add<0x143, 0xC, false>(v);
  return __int_as_float(__builtin_amdgcn_readlane(__float_as_int(v), 63));
}
// reduce valid in lanes 48..63 only (no readlane) - scan path, lane 63 stores
__device__ __forceinline__ float wave_red_hi(float v) {
  v = dpp_add<0xB1, 0xF, true>(v);
  v = dpp_add<0x4E, 0xF, true>(v);
  v = dpp_add<0x141, 0xF, true>(v);
  v = dpp_add<0x140, 0xF, true>(v);
  v = dpp_add<0x142, 0xA, false>(v);
  v = dpp_add<0x143, 0xC, false>(v);
  return v;
}

__device__ __forceinline__ unsigned short f2bf(float f) {
  union { float f; unsigned u; } c; c.f = f;
  const unsigned r = c.u + 0x7FFFu + ((c.u >> 16) & 1u);   // RNE
  return (unsigned short)(r >> 16);
}

// ---------------------------------------------------------------------------
// Kernel 1: proj = x @ W^T via bf16 MFMA (unchanged from R7).
// ---------------------------------------------------------------------------
__global__ __launch_bounds__(256) void gemm_proj(const float* __restrict__ x,
                                                 const float* __restrict__ W,
                                                 float* __restrict__ proj) {
  __shared__ unsigned short Al[64][72];
  __shared__ unsigned short Bl[256][72];
  const int tid = threadIdx.x;
  const int lane = tid & 63;
  const int wv = tid >> 6;
  const int m0 = blockIdx.x * 64;
  const int nw0 = wv * 64;

  f32x4 acc[4][4];
#pragma unroll
  for (int m = 0; m < 4; ++m)
#pragma unroll
    for (int n = 0; n < 4; ++n) acc[m][n] = (f32x4){0.f, 0.f, 0.f, 0.f};

  const int arow = tid >> 2;
  const int akb = (tid & 3) * 16;

  for (int k0 = 0; k0 < D_SZ; k0 += 64) {
    {
      const float* src = &x[(size_t)(m0 + arow) * D_SZ + k0 + akb];
      unsigned short tmp[16];
#pragma unroll
      for (int c = 0; c < 4; ++c) {
        const float4 f = *reinterpret_cast<const float4*>(src + c * 4);
        tmp[c * 4 + 0] = f2bf(f.x); tmp[c * 4 + 1] = f2bf(f.y);
        tmp[c * 4 + 2] = f2bf(f.z); tmp[c * 4 + 3] = f2bf(f.w);
      }
      *reinterpret_cast<bf16x8*>(&Al[arow][akb]) =
          *reinterpret_cast<bf16x8*>(&tmp[0]);
      *reinterpret_cast<bf16x8*>(&Al[arow][akb + 8]) =
          *reinterpret_cast<bf16x8*>(&tmp[8]);
    }
    {
      const float* src = &W[(size_t)tid * D_SZ + k0];
#pragma unroll
      for (int h = 0; h < 4; ++h) {
        unsigned short tmp[16];
#pragma unroll
        for (int c = 0; c < 4; ++c) {
          const float4 f = *reinterpret_cast<const float4*>(src + h * 16 + c * 4);
          tmp[c * 4 + 0] = f2bf(f.x); tmp[c * 4 + 1] = f2bf(f.y);
          tmp[c * 4 + 2] = f2bf(f.z); tmp[c * 4 + 3] = f2bf(f.w);
        }
        *reinterpret_cast<bf16x8*>(&Bl[tid][h * 16]) =
            *reinterpret_cast<bf16x8*>(&tmp[0]);
        *reinterpret_cast<bf16x8*>(&Bl[tid][h * 16 + 8]) =
            *reinterpret_cast<bf16x8*>(&tmp[8]);
      }
    }
    __syncthreads();
    const int fr = lane & 15;
#pragma unroll
    for (int kk = 0; kk < 64; kk += 32) {
      const int kof = kk + (lane >> 4) * 8;
      bf16x8 af[4], bfr[4];
#pragma unroll
      for (int m = 0; m < 4; ++m)
        af[m] = *reinterpret_cast<const bf16x8*>(&Al[m * 16 + fr][kof]);
#pragma unroll
      for (int n = 0; n < 4; ++n)
        bfr[n] = *reinterpret_cast<const bf16x8*>(&Bl[nw0 + n * 16 + fr][kof]);
#pragma unroll
      for (int m = 0; m < 4; ++m)
#pragma unroll
        for (int n = 0; n < 4; ++n)
          acc[m][n] = __builtin_amdgcn_mfma_f32_16x16x32_bf16(
              af[m], bfr[n], acc[m][n], 0, 0, 0);
    }
    __syncthreads();
  }

  const int col = lane & 15;
  const int rb = (lane >> 4) * 4;
#pragma unroll
  for (int m = 0; m < 4; ++m)
#pragma unroll
    for (int n = 0; n < 4; ++n)
#pragma unroll
      for (int r = 0; r < 4; ++r)
        proj[(size_t)(m0 + m * 16 + rb + r) * NOUT + nw0 + n * 16 + col] =
            acc[m][n][r];
}

// ---------------------------------------------------------------------------
// Kernel 2: per (t,b) row, in-place repack: [ (kn,q) x64 | (v,dec) x64 ]
// ---------------------------------------------------------------------------
__global__ __launch_bounds__(256) void norm_gate(float* __restrict__ proj,
                                                 const float* __restrict__ b_gate) {
  const int wid = threadIdx.x >> 6;
  const int lane = threadIdx.x & 63;
  const int m = blockIdx.x * 4 + wid;
  float* p = proj + (size_t)m * NOUT;
  const float kf = p[lane];
  const float vf = p[64 + lane];
  const float qf = p[128 + lane];
  const float gf = p[192 + lane];
  const float bg = b_gate[lane];
  const float ss = wave_red(kf * kf);
  const float kn = kf / (sqrtf(ss) + 1e-6f);
  const float dec = 1.f / (1.f + expf(-(gf + bg)));
  asm volatile("s_waitcnt vmcnt(0)" ::: "memory");
  float2* pp = reinterpret_cast<float2*>(p);
  float2 a; a.x = kn; a.y = qf;
  float2 c; c.x = vf; c.y = dec;
  pp[lane] = a;
  pp[64 + lane] = c;
}

// ---------------------------------------------------------------------------
// Kernel 3: Gram precompute (unchanged).
// ---------------------------------------------------------------------------
__global__ __launch_bounds__(256) void gram_kernel(const float* __restrict__ proj,
                                                   float* __restrict__ gram) {
  const int wid = threadIdx.x >> 6;
  const int lane = threadIdx.x & 63;
  const int gw = blockIdx.x * 4 + wid;
  const int a = gw & 7;
  const int grp = gw >> 3;                  // b*NBLK + blk
  const int blk = grp & (NBLK - 1);
  const int b = grp >> 8;
  const int t0 = blk * U_BLK;
  const float2* base = reinterpret_cast<const float2*>(proj);

  float2 knq[8];
#pragma unroll
  for (int c = 0; c < 8; ++c)
    knq[c] = base[(size_t)((t0 + c) * B_SZ + b) * 128 + lane];
  const float2 mine = base[(size_t)((t0 + a) * B_SZ + b) * 128 + lane];

  float row[8];
#pragma unroll
  for (int c = 0; c < 8; ++c) {
    const float lhs = (c > a) ? mine.x : mine.y;
    row[c] = wave_red(lhs * knq[c].x);
  }
  if (lane == 0) {
    float* dst = gram + ((size_t)grp * 64 + a * 8);
    float4 r0, r1;
    r0.x = row[0]; r0.y = row[1]; r0.z = row[2]; r0.w = row[3];
    r1.x = row[4]; r1.y = row[5]; r1.z = row[6]; r1.w = row[7];
    *reinterpret_cast<float4*>(dst) = r0;
    *reinterpret_cast<float4*>(dst + 4) = r1;
  }
}

// ---------------------------------------------------------------------------
// Kernel 4: scan.  512 blocks x 4 waves = 2048 waves (2/SIMD).
// Block = (b, i-pair); waves (chain, role): chain in {0,1} -> i = ibase+chain,
// role 0 computes the 8 S.kn reductions, role 1 the 8 S.q reductions;
// 16 scalars exchanged via LDS, recurrence duplicated in both waves.
// Gram: uniform loads -> SGPRs (s_load), no readlanes in recurrence.
// 2-buffer LDS staging (R6 style).
// ---------------------------------------------------------------------------
__global__ __launch_bounds__(256, 1) void scan_kernel(
    const float* __restrict__ proj, const float* __restrict__ gram,
    const float* __restrict__ S0, float* __restrict__ out,
    float* __restrict__ Sfin) {
  const int tid = threadIdx.x;
  const int wid = tid >> 6;          // 0..3
  const int lane = tid & 63;
  const int chain = wid >> 1;        // 0,1
  const int role = wid & 1;          // 0: kn, 1: q
  const int bid = blockIdx.x;
  const int b = (bid & 7) | (((bid >> 8) & 1) << 3);   // same XCD per b
  const int i = (((bid >> 3) & 31) << 1) | chain;

  __shared__ float lds[2][U_BLK * 256];    // 2 x 8 KB staging
  __shared__ float xch[2][16];             // per-chain {ra[8], rb[8]}

  float S = S0[(size_t)b * 4096 + i * 64 + lane];
  const int r0 = wid * 2;                  // staging rows for this wave
  float4 st0, st1;

#define GLOAD(blkv)                                                           \
  {                                                                           \
    const size_t g0 = ((size_t)(((blkv) * U_BLK + r0) * B_SZ + b)) * NOUT;    \
    st0 = *reinterpret_cast<const float4*>(&proj[g0 + lane * 4]);             \
    st1 = *reinterpret_cast<const float4*>(&proj[g0 + (size_t)B_SZ * NOUT +   \
                                                 lane * 4]);                  \
  }

#define LWRITE(bufv)                                                          \
  {                                                                           \
    *reinterpret_cast<float4*>(&lds[bufv][r0 * 256 + lane * 4]) = st0;        \
    *reinterpret_cast<float4*>(&lds[bufv][(r0 + 1) * 256 + lane * 4]) = st1;  \
  }

  GLOAD(0)
  LWRITE(0)
  __syncthreads();

  for (int blk = 0; blk < NBLK; ++blk) {
    const int buf = blk & 1;
    if (blk + 1 < NBLK) GLOAD(blk + 1)

    // gram scalars for this block: uniform address -> s_loads into SGPRs
    const float* gp = gram + (((size_t)b * NBLK + blk) << 6);
    float g[64];
#pragma unroll
    for (int z = 0; z < 64; ++z) g[z] = gp[z];

    // per-step vectors from LDS
    float2 knqv[8], vdv[8];
#pragma unroll
    for (int u = 0; u < 8; ++u) {
      knqv[u] = *reinterpret_cast<const float2*>(&lds[buf][u * 256 + lane * 2]);
      vdv[u] = *reinterpret_cast<const float2*>(&lds[buf][u * 256 + 128 + i * 2]);
    }

    // role-split reductions (valid in lanes 48..63)
    float red[8];
#pragma unroll
    for (int u = 0; u < 8; ++u) {
      const float m = role ? knqv[u].y : knqv[u].x;
      red[u] = wave_red_hi(S * m);
    }
    if (lane == 63) {
      float* dst = &xch[chain][role * 8];
#pragma unroll
      for (int u = 0; u < 8; ++u) dst[u] = red[u];
    }
    __syncthreads();

    float acc[8], sac[8];
    {
      const float4 a0 = *reinterpret_cast<const float4*>(&xch[chain][0]);
      const float4 a1 = *reinterpret_cast<const float4*>(&xch[chain][4]);
      const float4 b0 = *reinterpret_cast<const float4*>(&xch[chain][8]);
      const float4 b1 = *reinterpret_cast<const float4*>(&xch[chain][12]);
      acc[0] = a0.x; acc[1] = a0.y; acc[2] = a0.z; acc[3] = a0.w;
      acc[4] = a1.x; acc[5] = a1.y; acc[6] = a1.z; acc[7] = a1.w;
      sac[0] = b0.x; sac[1] = b0.y; sac[2] = b0.z; sac[3] = b0.w;
      sac[4] = b1.x; sac[5] = b1.y; sac[6] = b1.z; sac[7] = b1.w;
    }

    // prefix products + reciprocals
    float c[9], rc[8];
    c[0] = 1.f;
#pragma unroll
    for (int u = 0; u < 8; ++u) {
      c[u + 1] = c[u] * vdv[u].y;
      rc[u] = __builtin_amdgcn_rcpf(c[u + 1]);
    }

    // factored UT-transform recurrence (verified R6)
    float dp[8], sqv[8];
#pragma unroll
    for (int w = 0; w < 8; ++w) {
      const float d = fmaf(-c[w], acc[w], vdv[w].x);
      dp[w] = d * rc[w];
      sqv[w] = fmaf(c[w + 1], sac[w], d * g[w * 8 + w]);
#pragma unroll
      for (int u = w + 1; u < 8; ++u) {
        acc[u] = fmaf(dp[w], g[w * 8 + u], acc[u]);   // G[w][u]
        sac[u] = fmaf(dp[w], g[u * 8 + w], sac[u]);   // H[u][w]
      }
    }
    float tacc = S;
#pragma unroll
    for (int w = 0; w < 8; ++w) tacc = fmaf(dp[w], knqv[w].x, tacc);
    S = c[8] * tacc;

    if (blk + 1 < NBLK) LWRITE(buf ^ 1)

    if (role == 1 && lane == 0) {
      const size_t ob = (size_t)blk * U_BLK * (B_SZ * N_SZ) + b * N_SZ + i;
#pragma unroll
      for (int u = 0; u < 8; ++u)
        out[ob + (size_t)u * (B_SZ * N_SZ)] = sqv[u];   // raw sq; silu later
    }
    __syncthreads();
  }

  if (role == 0) Sfin[(size_t)b * 4096 + i * 64 + lane] = S;
#undef GLOAD
#undef LWRITE
}

// ---------------------------------------------------------------------------
// Kernel 5: out <- sq^2 * sigmoid(sq).  2048*256*4 = 2,097,152 elems exactly.
// ---------------------------------------------------------------------------
__global__ __launch_bounds__(256) void silu_pp(float* __restrict__ o) {
  const size_t idx = ((size_t)blockIdx.x * 256 + threadIdx.x) * 4;
  float4 v = *reinterpret_cast<float4*>(&o[idx]);
  v.x = v.x * v.x * __fdividef(1.f, 1.f + __expf(-v.x));
  v.y = v.y * v.y * __fdividef(1.f, 1.f + __expf(-v.y));
  v.z = v.z * v.z * __fdividef(1.f, 1.f + __expf(-v.z));
  v.w = v.w * v.w * __fdividef(1.f, 1.f + __expf(-v.w));
  *reinterpret_cast<float4*>(&o[idx]) = v;
}

// ---------------------------------------------------------------------------
extern "C" void kernel_launch(void* const* d_in, const int* in_sizes, int n_in,
                              void* d_out, int out_size, void* d_ws, size_t ws_size,
                              hipStream_t stream) {
  const float* x      = (const float*)d_in[0];
  const float* S0     = (const float*)d_in[1];
  const float* W      = (const float*)d_in[2];
  const float* b_gate = (const float*)d_in[3];
  float* out  = (float*)d_out;
  float* proj = (float*)d_ws;                       // 33.55 MB
  float* gram = (float*)((char*)d_ws + (size_t)M_ROWS * NOUT * 4);  // +1 MB

  hipLaunchKernelGGL(gemm_proj, dim3(M_ROWS / 64), dim3(256), 0, stream,
                     x, W, proj);
  hipLaunchKernelGGL(norm_gate, dim3(M_ROWS / 4), dim3(256), 0, stream,
                     proj, b_gate);
  hipLaunchKernelGGL(gram_kernel, dim3(32768 / 4), dim3(256), 0, stream,
                     proj, gram);
  hipLaunchKernelGGL(scan_kernel, dim3(512), dim3(256), 0, stream,
                     proj, gram, S0, out, out + (size_t)T_STEPS * B_SZ * N_SZ);
  hipLaunchKernelGGL(silu_pp, dim3(2048), dim3(256), 0, stream, out);
}